// Round 15
// baseline (125.829 us; speedup 1.0000x reference)
//
#include <hip/hip_runtime.h>

#define HWPIX 589824
#define Wdim 768
#define Bdim 4
#define Kdim 16
#define NBINS 2048
#define RANGE_F 16.0f
#define BIN_W (RANGE_F / NBINS)
#define INV_BIN_W (NBINS / RANGE_F)
#define EPSf 1e-6f
#define QCLIP 13.8155106f   /* -log(1e-6): q >= QCLIP  <=>  phi clamps to EPS */

#define Q4 (HWPIX / 4)      // 147456 float4 groups per channel
#define NSB 192             // blocks per batch
#define NBLK (NSB * Bdim)   // 768 blocks
#define GPI (NSB * 256)     // float4-groups per p-iteration per batch (3 iters)

// ws float offsets
#define ACC_OFF 0                      // [B][K][5]
#define LOVARR_OFF 724                 // [64]
#define HIST_OFF_F 1024                // uint hist[B*K][2][NBINS]
#define NHIST (Bdim * Kdim * 2 * NBINS)
// hist tail: [NHIST..NHIST+63] = posnh, [NHIST+64] = completion counter
#define HTAIL 80
#define SPART_OFF (HIST_OFF_F + NHIST + 128)       // float [NBLK][80]
#define MPART_OFF (SPART_OFF + NBLK * 80)          // float [NBLK][2]

__global__ __launch_bounds__(256, 3) void k_stats(const float* __restrict__ yp,
                                                  const int* __restrict__ yt,
                                                  float* __restrict__ ws,
                                                  unsigned* __restrict__ hist) {
    int b = blockIdx.y;
    int lane = threadIdx.x & 63;
    int wv = threadIdx.x >> 6;
    __shared__ float lpart[4][80];

    // zero hist + posnh + completion counter (folded memset)
    {
        int gtid = (b * NSB + blockIdx.x) * 256 + threadIdx.x;
        for (int i = gtid; i < NHIST + HTAIL; i += NBLK * 256) hist[i] = 0u;
    }

    const float4* bp4 = (const float4*)(yp + (size_t)b * 5 * HWPIX);
    const int4* bt4 = (const int4*)(yt + (size_t)b * HWPIX);

    float acc[80];
#pragma unroll
    for (int v = 0; v < 80; ++v) acc[v] = 0.f;

    for (int p = 0; p < 3; ++p) {
        int g = p * GPI + blockIdx.x * 256 + threadIdx.x;
        float4 voy = bp4[g];
        float4 vox = bp4[g + Q4];
        float4 vsy = bp4[g + 2 * Q4];
        float4 vsx = bp4[g + 3 * Q4];
        int4 vt = bt4[g];
        int hwb = g * 4;
        float oy[4] = {voy.x, voy.y, voy.z, voy.w};
        float ox[4] = {vox.x, vox.y, vox.z, vox.w};
        float sy[4] = {vsy.x, vsy.y, vsy.z, vsy.w};
        float sx[4] = {vsx.x, vsx.y, vsx.z, vsx.w};
        int tt[4] = {vt.x, vt.y, vt.z, vt.w};
#pragma unroll
        for (int j = 0; j < 4; ++j) {
            int hw = hwb + j;
            int h = hw / Wdim;
            int w = hw - h * Wdim;
            int own = tt[j] - 1;
            float vy = (float)h + oy[j];
            float vx = (float)w + ox[j];
#pragma unroll
            for (int k = 0; k < Kdim; ++k) {
                float m = (own == k) ? 1.0f : 0.0f;
                acc[k * 5 + 0] += m;
                acc[k * 5 + 1] = fmaf(m, vy, acc[k * 5 + 1]);
                acc[k * 5 + 2] = fmaf(m, vx, acc[k * 5 + 2]);
                acc[k * 5 + 3] = fmaf(m, sy[j], acc[k * 5 + 3]);
                acc[k * 5 + 4] = fmaf(m, sx[j], acc[k * 5 + 4]);
            }
        }
    }

    // fold across half-waves: lanes 0-31 own values 0..39, lanes 32-63 own 40..79
    bool lo = (lane < 32);
#pragma unroll
    for (int v = 0; v < 40; ++v) {
        float send = lo ? acc[v + 40] : acc[v];
        float got = __shfl_xor(send, 32);
        acc[v] += lo ? got : 0.f;
        acc[v + 40] += lo ? 0.f : got;
    }
#pragma unroll
    for (int v = 0; v < 40; ++v) {
        float x = lo ? acc[v] : acc[v + 40];
#pragma unroll
        for (int o = 16; o >= 1; o >>= 1) x += __shfl_xor(x, o);
        if ((lane & 31) == 0) lpart[wv][lo ? v : v + 40] = x;
    }
    __syncthreads();
    if (threadIdx.x < 80) {
        float v = lpart[0][threadIdx.x] + lpart[1][threadIdx.x] +
                  lpart[2][threadIdx.x] + lpart[3][threadIdx.x];
        ws[SPART_OFF + (size_t)(b * NSB + blockIdx.x) * 80 + threadIdx.x] = v;
    }
}

// 80 blocks x 256: one wave per output (320 outputs)
__global__ void k_centers2(float* __restrict__ ws) {
    int wv = threadIdx.x >> 6;
    int lane = threadIdx.x & 63;
    int gw = blockIdx.x * 4 + wv;        // 0..319
    int b = gw / 80, idx = gw - b * 80;
    const float* sp = ws + SPART_OFF + (size_t)b * NSB * 80 + idx;
    float x = sp[(size_t)lane * 80] + sp[(size_t)(lane + 64) * 80] +
              sp[(size_t)(lane + 128) * 80];
#pragma unroll
    for (int o = 32; o >= 1; o >>= 1) x += __shfl_xor(x, o);
    if (lane == 0) ws[ACC_OFF + b * 80 + idx] = x;
}

__global__ __launch_bounds__(256, 3) void k_main(const float* __restrict__ yp,
                                                 const int* __restrict__ yt,
                                                 float* __restrict__ ws,
                                                 unsigned* __restrict__ hist) {
    int b = blockIdx.y;
    int lane = threadIdx.x & 63;
    int wv = threadIdx.x >> 6;
    __shared__ float ck_s[32];
    __shared__ float4 msw_s[17];
    __shared__ float part[4][2];
    // prologue: centers/means/weights for this batch from ACC
    if (threadIdx.x < 16) {
        int k = threadIdx.x;
        const float* a = ws + ACC_OFF + (size_t)b * 80 + k * 5;
        float cnt = a[0];
        float safe = fmaxf(cnt, 1.0f);
        float inv = 1.0f / safe;
        ck_s[k * 2 + 0] = a[1] * inv;
        ck_s[k * 2 + 1] = a[2] * inv;
        float4 mw;
        mw.x = a[3] * inv;
        mw.y = a[4] * inv;
        mw.z = (cnt > 0.f) ? 0.5f / cnt : 0.f;
        mw.w = 0.f;
        msw_s[k] = mw;
    }
    if (threadIdx.x == 16) msw_s[16] = (float4){0.f, 0.f, 0.f, 0.f};
    __syncthreads();

    float cky[Kdim], ckx[Kdim];
#pragma unroll
    for (int k = 0; k < Kdim; ++k) {
        cky[k] = ck_s[k * 2];
        ckx[k] = ck_s[k * 2 + 1];
    }

    unsigned* hb = hist + (size_t)(b * Kdim) * 2 * NBINS;
    unsigned* posnh = hist + (size_t)NHIST;
    const float4* bp4 = (const float4*)(yp + (size_t)b * 5 * HWPIX);
    const int4* bt4 = (const int4*)(yt + (size_t)b * HWPIX);

    float varsum = 0.f, ssum = 0.f;
    for (int p = 0; p < 3; ++p) {
        int g = p * GPI + blockIdx.x * 256 + threadIdx.x;
        float4 voy = bp4[g];
        float4 vox = bp4[g + Q4];
        float4 vsy = bp4[g + 2 * Q4];
        float4 vsx = bp4[g + 3 * Q4];
        float4 vse = bp4[g + 4 * Q4];
        int4 vt = bt4[g];
        int hwb = g * 4;
        float oy[4] = {voy.x, voy.y, voy.z, voy.w};
        float ox[4] = {vox.x, vox.y, vox.z, vox.w};
        float sya[4] = {vsy.x, vsy.y, vsy.z, vsy.w};
        float sxa[4] = {vsx.x, vsx.y, vsx.z, vsx.w};
        float sea[4] = {vse.x, vse.y, vse.z, vse.w};
        int tt[4] = {vt.x, vt.y, vt.z, vt.w};
#pragma unroll
        for (int j = 0; j < 4; ++j) {
            int hw = hwb + j;
            int h = hw / Wdim;
            int w = hw - h * Wdim;
            int own = tt[j] - 1;
            float sy = sya[j], sx = sxa[j];
            float ey = (float)h + oy[j], ex = (float)w + ox[j];
            float sby = fmaxf(sy, EPSf), sbx = fmaxf(sx, EPSf);
            float iy = 0.5f / (sby * sby), ix = 0.5f / (sbx * sbx);

            unsigned sm = 0;
#pragma unroll
            for (int k = 0; k < Kdim; ++k) {
                float dy = ey - cky[k];
                float dx = ex - ckx[k];
                float q = fmaf(dy * dy, iy, dx * dx * ix);
                if (q < QCLIP) sm |= (1u << k);
            }
            // dev + var contribution (slot 16 = zeros for unlabeled)
            int ow = (own >= 0) ? own : 16;
            float4 mw = msw_s[ow];
            float devv = fabsf(sy - mw.x) + fabsf(sx - mw.y);
            varsum = fmaf(devv, mw.z, varsum);

            float st = (own >= 0) ? EPSf : 0.f;
            while (sm) {  // rare slow path: near some center
                int k = __ffs(sm) - 1;
                sm &= sm - 1;
                float dy = ey - ck_s[k * 2];
                float dx = ex - ck_s[k * 2 + 1];
                float q = fmaf(dy * dy, iy, dx * dx * ix);
                float phi = expf(-q);
                phi = fminf(fmaxf(phi, EPSf), 1.0f - EPSf);
                float lg = logf(phi) - log1pf(-phi);
                bool isPos = (k == own);
                float e;
                if (isPos) {
                    st = phi;
                    atomicAdd(&posnh[b * Kdim + k], 1u);
                    e = 1.0f - lg;
                } else {
                    e = 1.0f + lg;
                }
                if (e > 0.f) {
                    int bin = (int)(e * INV_BIN_W);
                    if (bin > NBINS - 1) bin = NBINS - 1;
                    atomicAdd(&hb[(k * 2 + (isPos ? 1 : 0)) * NBINS + bin], 1u);
                }
            }
            float dd = sea[j] - st;
            ssum = fmaf(dd, dd, ssum);
        }
    }
#pragma unroll
    for (int o = 32; o >= 1; o >>= 1) {
        varsum += __shfl_xor(varsum, o);
        ssum += __shfl_xor(ssum, o);
    }
    if (lane == 0) {
        part[wv][0] = varsum;
        part[wv][1] = ssum;
    }
    __syncthreads();
    if (threadIdx.x < 2) {
        float v = part[0][threadIdx.x] + part[1][threadIdx.x] +
                  part[2][threadIdx.x] + part[3][threadIdx.x];
        ws[MPART_OFF + (size_t)(b * NSB + blockIdx.x) * 2 + threadIdx.x] = v;
    }
}

// One wave per (b,k): suffix-scan histogram top-down, trapezoid-integrate.
// Last block to finish also does the final combine (counter in hist[NHIST+64]).
__global__ void k_lovasz(float* __restrict__ ws, unsigned* __restrict__ hist,
                         float* __restrict__ out) {
    int i = blockIdx.x;  // 0..63
    int lane = threadIdx.x;
    float P = ws[ACC_OFF + i * 5];
    float res = 0.f;
    if (P >= 0.5f) {
        const unsigned* hn = hist + (size_t)i * 2 * NBINS;
        const unsigned* hp = hn + NBINS;
        const unsigned* posnh = hist + (size_t)NHIST;
        const float C_LO = logf(EPSf) - log1pf(-EPSf);
        const int HOTBIN = (int)((1.0f - C_LO) * INV_BIN_W);
        int deficit = (int)(P + 0.5f) - (int)posnh[i];
        int carry_p = 0, carry_n = 0;
        float Jtop = 0.f;
        float trap = 0.f;
        for (int c = NBINS / 64 - 1; c >= 0; --c) {
            int m = c * 64 + lane;
            int vp = (int)hp[m];
            int vn = (int)hn[m];
            if (m == HOTBIN) vp += deficit;
            for (int o = 1; o < 64; o <<= 1) {
                int tp = __shfl_down(vp, o);
                int tn = __shfl_down(vn, o);
                if (lane + o < 64) { vp += tp; vn += tn; }
            }
            float p_edge = (float)(carry_p + vp);
            float n_edge = (float)(carry_n + vn);
            float J = 1.0f - (P - p_edge) / (P + n_edge);
            float Jn = __shfl_down(J, 1);
            if (lane == 63) Jn = Jtop;
            trap += 0.5f * (J + Jn);
            carry_p += __shfl(vp, 0);
            carry_n += __shfl(vn, 0);
            Jtop = __shfl(J, 0);
        }
        for (int o = 1; o < 64; o <<= 1) {
            float t2 = __shfl_down(trap, o);
            if (lane + o < 64) trap += t2;
        }
        res = trap * BIN_W;
    }
    if (lane == 0) ws[LOVARR_OFF + i] = res;
    __threadfence();

    __shared__ unsigned ticket;
    if (lane == 0) ticket = atomicAdd(&hist[NHIST + 64], 1u);
    __syncthreads();
    if (ticket != 63u) return;

    float v = 0.f, s = 0.f, l = 0.f, pr = 0.f;
    for (int j = lane; j < NBLK; j += 64) {
        v += ws[MPART_OFF + 2 * j];
        s += ws[MPART_OFF + 2 * j + 1];
    }
    l = ws[LOVARR_OFF + lane];
    pr = (ws[ACC_OFF + lane * 5] > 0.f) ? 1.f : 0.f;
#pragma unroll
    for (int o = 32; o >= 1; o >>= 1) {
        v += __shfl_xor(v, o);
        s += __shfl_xor(s, o);
        l += __shfl_xor(l, o);
        pr += __shfl_xor(pr, o);
    }
    if (lane == 0) {
        float npres = fmaxf(pr, 1.0f);
        out[0] = l / npres + 10.0f * (v / npres) +
                 s / (float)((size_t)Bdim * HWPIX);
    }
}

extern "C" void kernel_launch(void* const* d_in, const int* in_sizes, int n_in,
                              void* d_out, int out_size, void* d_ws, size_t ws_size,
                              hipStream_t stream) {
    const float* yp = (const float*)d_in[0];
    const int* yt = (const int*)d_in[1];
    float* ws = (float*)d_ws;
    unsigned* hist = (unsigned*)((char*)d_ws + HIST_OFF_F * 4);

    dim3 g(NSB, Bdim);

    // Cooperative launches force all 768 blocks co-resident (no in-kernel
    // grid sync — launch mode only, to fix the ~11% occupancy trickle).
    {
        void* args[4] = {(void*)&yp, (void*)&yt, (void*)&ws, (void*)&hist};
        hipError_t e = hipLaunchCooperativeKernel((const void*)k_stats, g,
                                                  dim3(256), args, 0, stream);
        if (e != hipSuccess) {
            (void)hipGetLastError();
            k_stats<<<g, 256, 0, stream>>>(yp, yt, ws, hist);
        }
    }
    k_centers2<<<80, 256, 0, stream>>>(ws);
    {
        void* args[4] = {(void*)&yp, (void*)&yt, (void*)&ws, (void*)&hist};
        hipError_t e = hipLaunchCooperativeKernel((const void*)k_main, g,
                                                  dim3(256), args, 0, stream);
        if (e != hipSuccess) {
            (void)hipGetLastError();
            k_main<<<g, 256, 0, stream>>>(yp, yt, ws, hist);
        }
    }
    k_lovasz<<<64, 64, 0, stream>>>(ws, hist, (float*)d_out);
}

// Round 16
// 83.553 us; speedup vs baseline: 1.5060x; 1.5060x over previous
//
#include <hip/hip_runtime.h>

#define HWPIX 589824
#define Wdim 768
#define Bdim 4
#define Kdim 16
#define NBINS 2048
#define RANGE_F 16.0f
#define BIN_W (RANGE_F / NBINS)
#define INV_BIN_W (NBINS / RANGE_F)
#define EPSf 1e-6f
#define QCLIP 13.8155106f   /* -log(1e-6): q >= QCLIP  <=>  phi clamps to EPS */
#define RMARG 5.2600f       /* > sqrt(2*QCLIP): |dy| >= RMARG*sby => q >= QCLIP */

#define Q4 (HWPIX / 4)      // 147456 float4 groups per channel
#define NSB 192             // blocks per batch
#define NBLK (NSB * Bdim)   // 768 blocks
#define GPI (NSB * 256)     // float4-groups per p-iteration per batch (3 iters)

// ws float offsets
#define ACC_OFF 0                      // [B][K][5]
#define LOVARR_OFF 724                 // [64]
#define HIST_OFF_F 1024                // uint hist[B*K][2][NBINS]
#define NHIST (Bdim * Kdim * 2 * NBINS)
#define SPART_OFF (HIST_OFF_F + NHIST + 64)        // float [NBLK][80]
#define MPART_OFF (SPART_OFF + NBLK * 80)          // float [NBLK][2]

__global__ __launch_bounds__(256, 3) void k_stats(const float* __restrict__ yp,
                                                  const int* __restrict__ yt,
                                                  float* __restrict__ ws,
                                                  unsigned* __restrict__ hist) {
    int b = blockIdx.y;
    int lane = threadIdx.x & 63;
    int wv = threadIdx.x >> 6;
    __shared__ float lpart[4][80];

    // zero hist + posnh (folded memset; all 768 blocks participate)
    {
        int gtid = (b * NSB + blockIdx.x) * 256 + threadIdx.x;
        for (int i = gtid; i < NHIST + 64; i += NBLK * 256) hist[i] = 0u;
    }

    const float4* bp4 = (const float4*)(yp + (size_t)b * 5 * HWPIX);
    const int4* bt4 = (const int4*)(yt + (size_t)b * HWPIX);

    float acc[80];
#pragma unroll
    for (int v = 0; v < 80; ++v) acc[v] = 0.f;

    for (int p = 0; p < 3; ++p) {
        int g = p * GPI + blockIdx.x * 256 + threadIdx.x;
        float4 voy = bp4[g];
        float4 vox = bp4[g + Q4];
        float4 vsy = bp4[g + 2 * Q4];
        float4 vsx = bp4[g + 3 * Q4];
        int4 vt = bt4[g];
        int hwb = g * 4;
        float oy[4] = {voy.x, voy.y, voy.z, voy.w};
        float ox[4] = {vox.x, vox.y, vox.z, vox.w};
        float sy[4] = {vsy.x, vsy.y, vsy.z, vsy.w};
        float sx[4] = {vsx.x, vsx.y, vsx.z, vsx.w};
        int tt[4] = {vt.x, vt.y, vt.z, vt.w};
#pragma unroll
        for (int j = 0; j < 4; ++j) {
            int hw = hwb + j;
            int h = hw / Wdim;
            int w = hw - h * Wdim;
            int own = tt[j] - 1;
            float vy = (float)h + oy[j];
            float vx = (float)w + ox[j];
#pragma unroll
            for (int k = 0; k < Kdim; ++k) {
                float m = (own == k) ? 1.0f : 0.0f;
                acc[k * 5 + 0] += m;
                acc[k * 5 + 1] = fmaf(m, vy, acc[k * 5 + 1]);
                acc[k * 5 + 2] = fmaf(m, vx, acc[k * 5 + 2]);
                acc[k * 5 + 3] = fmaf(m, sy[j], acc[k * 5 + 3]);
                acc[k * 5 + 4] = fmaf(m, sx[j], acc[k * 5 + 4]);
            }
        }
    }

    // fold across half-waves: lanes 0-31 own values 0..39, lanes 32-63 own 40..79
    bool lo = (lane < 32);
#pragma unroll
    for (int v = 0; v < 40; ++v) {
        float send = lo ? acc[v + 40] : acc[v];
        float got = __shfl_xor(send, 32);
        acc[v] += lo ? got : 0.f;
        acc[v + 40] += lo ? 0.f : got;
    }
#pragma unroll
    for (int v = 0; v < 40; ++v) {
        float x = lo ? acc[v] : acc[v + 40];
#pragma unroll
        for (int o = 16; o >= 1; o >>= 1) x += __shfl_xor(x, o);
        if ((lane & 31) == 0) lpart[wv][lo ? v : v + 40] = x;
    }
    __syncthreads();
    if (threadIdx.x < 80) {
        float v = lpart[0][threadIdx.x] + lpart[1][threadIdx.x] +
                  lpart[2][threadIdx.x] + lpart[3][threadIdx.x];
        ws[SPART_OFF + (size_t)(b * NSB + blockIdx.x) * 80 + threadIdx.x] = v;
    }
}

// 80 blocks x 256: one wave per output (320 outputs); lane sums 3 strided
// partials, butterfly-reduces, lane 0 stores ACC.
__global__ void k_centers2(float* __restrict__ ws) {
    int wv = threadIdx.x >> 6;
    int lane = threadIdx.x & 63;
    int gw = blockIdx.x * 4 + wv;        // 0..319
    int b = gw / 80, idx = gw - b * 80;
    const float* sp = ws + SPART_OFF + (size_t)b * NSB * 80 + idx;
    float x = sp[(size_t)lane * 80] + sp[(size_t)(lane + 64) * 80] +
              sp[(size_t)(lane + 128) * 80];
#pragma unroll
    for (int o = 32; o >= 1; o >>= 1) x += __shfl_xor(x, o);
    if (lane == 0) ws[ACC_OFF + b * 80 + idx] = x;
}

__global__ __launch_bounds__(256, 3) void k_main(const float* __restrict__ yp,
                                                 const int* __restrict__ yt,
                                                 float* __restrict__ ws,
                                                 unsigned* __restrict__ hist) {
    int b = blockIdx.y;
    int lane = threadIdx.x & 63;
    int wv = threadIdx.x >> 6;
    __shared__ float ck_s[32];
    __shared__ float4 msw_s[17];
    __shared__ float part[4][2];
    __shared__ float bb[4];   // bbox over present centers: ymin,ymax,xmin,xmax
    // prologue: compute centers/means/weights for this batch from ACC
    if (threadIdx.x < 16) {
        int k = threadIdx.x;
        const float* a = ws + ACC_OFF + (size_t)b * 80 + k * 5;
        float cnt = a[0];
        float safe = fmaxf(cnt, 1.0f);
        float inv = 1.0f / safe;
        ck_s[k * 2 + 0] = a[1] * inv;
        ck_s[k * 2 + 1] = a[2] * inv;
        float4 mw;
        mw.x = a[3] * inv;
        mw.y = a[4] * inv;
        mw.z = (cnt > 0.f) ? 0.5f / cnt : 0.f;
        mw.w = 0.f;
        msw_s[k] = mw;
    }
    if (threadIdx.x == 16) msw_s[16] = (float4){0.f, 0.f, 0.f, 0.f};
    __syncthreads();
    if (threadIdx.x == 0) {
        float ymin = 1e30f, ymax = -1e30f, xmin = 1e30f, xmax = -1e30f;
        for (int k = 0; k < Kdim; ++k) {
            float cnt = ws[ACC_OFF + (size_t)b * 80 + k * 5];
            if (cnt > 0.f) {
                float cy = ck_s[k * 2], cx = ck_s[k * 2 + 1];
                ymin = fminf(ymin, cy); ymax = fmaxf(ymax, cy);
                xmin = fminf(xmin, cx); xmax = fmaxf(xmax, cx);
            }
        }
        bb[0] = ymin; bb[1] = ymax; bb[2] = xmin; bb[3] = xmax;
    }
    __syncthreads();

    float cky[Kdim], ckx[Kdim];
#pragma unroll
    for (int k = 0; k < Kdim; ++k) {
        cky[k] = ck_s[k * 2];
        ckx[k] = ck_s[k * 2 + 1];
    }
    float bymin = bb[0], bymax = bb[1], bxmin = bb[2], bxmax = bb[3];

    unsigned* hb = hist + (size_t)(b * Kdim) * 2 * NBINS;
    unsigned* posnh = hist + (size_t)NHIST;
    const float4* bp4 = (const float4*)(yp + (size_t)b * 5 * HWPIX);
    const int4* bt4 = (const int4*)(yt + (size_t)b * HWPIX);

    float varsum = 0.f, ssum = 0.f;
    for (int p = 0; p < 3; ++p) {
        int g = p * GPI + blockIdx.x * 256 + threadIdx.x;
        float4 voy = bp4[g];
        float4 vox = bp4[g + Q4];
        float4 vsy = bp4[g + 2 * Q4];
        float4 vsx = bp4[g + 3 * Q4];
        float4 vse = bp4[g + 4 * Q4];
        int4 vt = bt4[g];
        int hwb = g * 4;
        float oy[4] = {voy.x, voy.y, voy.z, voy.w};
        float ox[4] = {vox.x, vox.y, vox.z, vox.w};
        float sya[4] = {vsy.x, vsy.y, vsy.z, vsy.w};
        float sxa[4] = {vsx.x, vsx.y, vsx.z, vsx.w};
        float sea[4] = {vse.x, vse.y, vse.z, vse.w};
        int tt[4] = {vt.x, vt.y, vt.z, vt.w};
#pragma unroll
        for (int j = 0; j < 4; ++j) {
            int hw = hwb + j;
            int h = hw / Wdim;
            int w = hw - h * Wdim;
            int own = tt[j] - 1;
            float sy = sya[j], sx = sxa[j];
            float ey = (float)h + oy[j], ex = (float)w + ox[j];
            float sby = fmaxf(sy, EPSf), sbx = fmaxf(sx, EPSf);

            float st = (own >= 0) ? EPSf : 0.f;
            // bbox prune: |dy| >= RMARG*sby for ALL centers => every q >= QCLIP
            float ry = RMARG * sby, rx = RMARG * sbx;
            bool maybe = (ey >= bymin - ry) && (ey <= bymax + ry) &&
                         (ex >= bxmin - rx) && (ex <= bxmax + rx);
            if (maybe) {
                float iy = 0.5f / (sby * sby), ix = 0.5f / (sbx * sbx);
                unsigned sm = 0;
#pragma unroll
                for (int k = 0; k < Kdim; ++k) {
                    float dy = ey - cky[k];
                    float dx = ex - ckx[k];
                    float q = fmaf(dy * dy, iy, dx * dx * ix);
                    if (q < QCLIP) sm |= (1u << k);
                }
                while (sm) {  // rare slow path: near some center
                    int k = __ffs(sm) - 1;
                    sm &= sm - 1;
                    float dy = ey - ck_s[k * 2];
                    float dx = ex - ck_s[k * 2 + 1];
                    float q = fmaf(dy * dy, iy, dx * dx * ix);
                    float phi = expf(-q);
                    phi = fminf(fmaxf(phi, EPSf), 1.0f - EPSf);
                    float lg = logf(phi) - log1pf(-phi);
                    bool isPos = (k == own);
                    float e;
                    if (isPos) {
                        st = phi;
                        atomicAdd(&posnh[b * Kdim + k], 1u);
                        e = 1.0f - lg;
                    } else {
                        e = 1.0f + lg;
                    }
                    if (e > 0.f) {
                        int bin = (int)(e * INV_BIN_W);
                        if (bin > NBINS - 1) bin = NBINS - 1;
                        atomicAdd(&hb[(k * 2 + (isPos ? 1 : 0)) * NBINS + bin], 1u);
                    }
                }
            }
            // dev + var contribution (slot 16 = zeros for unlabeled)
            int ow = (own >= 0) ? own : 16;
            float4 mw = msw_s[ow];
            float devv = fabsf(sy - mw.x) + fabsf(sx - mw.y);
            varsum = fmaf(devv, mw.z, varsum);
            float dd = sea[j] - st;
            ssum = fmaf(dd, dd, ssum);
        }
    }
#pragma unroll
    for (int o = 32; o >= 1; o >>= 1) {
        varsum += __shfl_xor(varsum, o);
        ssum += __shfl_xor(ssum, o);
    }
    if (lane == 0) {
        part[wv][0] = varsum;
        part[wv][1] = ssum;
    }
    __syncthreads();
    if (threadIdx.x < 2) {
        float v = part[0][threadIdx.x] + part[1][threadIdx.x] +
                  part[2][threadIdx.x] + part[3][threadIdx.x];
        ws[MPART_OFF + (size_t)(b * NSB + blockIdx.x) * 2 + threadIdx.x] = v;
    }
}

// One wave per (b,k): suffix-scan histogram top-down, trapezoid-integrate
// J(t) = 1 - (P - p(t))/(P + n(t)).  Clamped positives enter implicitly as
// deficit = P - posnh at HOTBIN.
__global__ void k_lovasz(float* __restrict__ ws, const unsigned* __restrict__ hist) {
    int i = blockIdx.x;  // 0..63
    int lane = threadIdx.x;
    float P = ws[ACC_OFF + i * 5];
    if (P < 0.5f) {
        if (lane == 0) ws[LOVARR_OFF + i] = 0.f;
        return;
    }
    const unsigned* hn = hist + (size_t)i * 2 * NBINS;
    const unsigned* hp = hn + NBINS;
    const unsigned* posnh = hist + (size_t)NHIST;
    const float C_LO = logf(EPSf) - log1pf(-EPSf);
    const int HOTBIN = (int)((1.0f - C_LO) * INV_BIN_W);
    int deficit = (int)(P + 0.5f) - (int)posnh[i];
    int carry_p = 0, carry_n = 0;
    float Jtop = 0.f;
    float trap = 0.f;
    for (int c = NBINS / 64 - 1; c >= 0; --c) {
        int m = c * 64 + lane;
        int vp = (int)hp[m];
        int vn = (int)hn[m];
        if (m == HOTBIN) vp += deficit;
        for (int o = 1; o < 64; o <<= 1) {
            int tp = __shfl_down(vp, o);
            int tn = __shfl_down(vn, o);
            if (lane + o < 64) { vp += tp; vn += tn; }
        }
        float p_edge = (float)(carry_p + vp);
        float n_edge = (float)(carry_n + vn);
        float J = 1.0f - (P - p_edge) / (P + n_edge);
        float Jn = __shfl_down(J, 1);
        if (lane == 63) Jn = Jtop;
        trap += 0.5f * (J + Jn);
        carry_p += __shfl(vp, 0);
        carry_n += __shfl(vn, 0);
        Jtop = __shfl(J, 0);
    }
    for (int o = 1; o < 64; o <<= 1) {
        float t2 = __shfl_down(trap, o);
        if (lane + o < 64) trap += t2;
    }
    if (lane == 0) ws[LOVARR_OFF + i] = trap * BIN_W;
}

__global__ void k_final(const float* __restrict__ ws, float* __restrict__ out) {
    __shared__ float r0[256], r1[256], r2[256], r3[256];
    int t = threadIdx.x;
    float v = 0.f, s = 0.f, l = 0.f, pr = 0.f;
    for (int j = t; j < NBLK; j += 256) {
        v += ws[MPART_OFF + 2 * j];
        s += ws[MPART_OFF + 2 * j + 1];
    }
    if (t < 64) {
        l = ws[LOVARR_OFF + t];
        pr = (ws[ACC_OFF + t * 5] > 0.f) ? 1.f : 0.f;
    }
    r0[t] = v; r1[t] = s; r2[t] = l; r3[t] = pr;
    __syncthreads();
    for (int o = 128; o > 0; o >>= 1) {
        if (t < o) {
            r0[t] += r0[t + o]; r1[t] += r1[t + o];
            r2[t] += r2[t + o]; r3[t] += r3[t + o];
        }
        __syncthreads();
    }
    if (t == 0) {
        float npres = fmaxf(r3[0], 1.0f);
        out[0] = r2[0] / npres + 10.0f * (r0[0] / npres) +
                 r1[0] / (float)((size_t)Bdim * HWPIX);
    }
}

extern "C" void kernel_launch(void* const* d_in, const int* in_sizes, int n_in,
                              void* d_out, int out_size, void* d_ws, size_t ws_size,
                              hipStream_t stream) {
    const float* yp = (const float*)d_in[0];
    const int* yt = (const int*)d_in[1];
    float* ws = (float*)d_ws;
    unsigned* hist = (unsigned*)((char*)d_ws + HIST_OFF_F * 4);

    dim3 g(NSB, Bdim);
    k_stats<<<g, 256, 0, stream>>>(yp, yt, ws, hist);
    k_centers2<<<80, 256, 0, stream>>>(ws);
    k_main<<<g, 256, 0, stream>>>(yp, yt, ws, hist);
    k_lovasz<<<64, 64, 0, stream>>>(ws, hist);
    k_final<<<1, 256, 0, stream>>>(ws, (float*)d_out);
}

// Round 17
// 82.988 us; speedup vs baseline: 1.5162x; 1.0068x over previous
//
#include <hip/hip_runtime.h>

#define HWPIX 589824
#define Wdim 768
#define Bdim 4
#define Kdim 16
#define NBINS 2048
#define RANGE_F 16.0f
#define BIN_W (RANGE_F / NBINS)
#define INV_BIN_W (NBINS / RANGE_F)
#define EPSf 1e-6f
#define QCLIP 13.8155106f   /* -log(1e-6): q >= QCLIP  <=>  phi clamps to EPS */
#define RMARG 5.2600f       /* > sqrt(2*QCLIP) */

#define Q4 (HWPIX / 4)      // 147456 float4 groups per channel
#define NSB 192             // blocks per batch
#define NBLK (NSB * Bdim)   // 768 blocks
#define GPI (NSB * 256)     // float4-groups per group-pass per batch (3 passes)

// ws float offsets
#define ACC_OFF 0                      // [B][K][5]
#define LOVARR_OFF 724                 // [64]
#define HIST_OFF_F 1024                // uint hist[B*K][2][NBINS]
#define NHIST (Bdim * Kdim * 2 * NBINS)
#define SPART_OFF (HIST_OFF_F + NHIST + 64)        // float [NBLK][80]
#define MPART_OFF (SPART_OFF + NBLK * 80)          // float [NBLK][2]

__global__ __launch_bounds__(256, 3) void k_stats(const float* __restrict__ yp,
                                                  const int* __restrict__ yt,
                                                  float* __restrict__ ws,
                                                  unsigned* __restrict__ hist) {
    int b = blockIdx.y;
    int lane = threadIdx.x & 63;
    int wv = threadIdx.x >> 6;
    __shared__ float lpart[4][80];

    // zero hist + posnh (folded memset; all 768 blocks participate)
    {
        int gtid = (b * NSB + blockIdx.x) * 256 + threadIdx.x;
        for (int i = gtid; i < NHIST + 64; i += NBLK * 256) hist[i] = 0u;
    }

    const float4* bp4 = (const float4*)(yp + (size_t)b * 5 * HWPIX);
    const int4* bt4 = (const int4*)(yt + (size_t)b * HWPIX);

    float acc[80];
#pragma unroll
    for (int v = 0; v < 80; ++v) acc[v] = 0.f;

    for (int p = 0; p < 3; ++p) {
        int g = p * GPI + blockIdx.x * 256 + threadIdx.x;
        float4 voy = bp4[g];
        float4 vox = bp4[g + Q4];
        float4 vsy = bp4[g + 2 * Q4];
        float4 vsx = bp4[g + 3 * Q4];
        int4 vt = bt4[g];
        int hwb = g * 4;
        float oy[4] = {voy.x, voy.y, voy.z, voy.w};
        float ox[4] = {vox.x, vox.y, vox.z, vox.w};
        float sy[4] = {vsy.x, vsy.y, vsy.z, vsy.w};
        float sx[4] = {vsx.x, vsx.y, vsx.z, vsx.w};
        int tt[4] = {vt.x, vt.y, vt.z, vt.w};
#pragma unroll
        for (int j = 0; j < 4; ++j) {
            int hw = hwb + j;
            int h = hw / Wdim;
            int w = hw - h * Wdim;
            int own = tt[j] - 1;
            float vy = (float)h + oy[j];
            float vx = (float)w + ox[j];
#pragma unroll
            for (int k = 0; k < Kdim; ++k) {
                float m = (own == k) ? 1.0f : 0.0f;
                acc[k * 5 + 0] += m;
                acc[k * 5 + 1] = fmaf(m, vy, acc[k * 5 + 1]);
                acc[k * 5 + 2] = fmaf(m, vx, acc[k * 5 + 2]);
                acc[k * 5 + 3] = fmaf(m, sy[j], acc[k * 5 + 3]);
                acc[k * 5 + 4] = fmaf(m, sx[j], acc[k * 5 + 4]);
            }
        }
    }

    bool lo = (lane < 32);
#pragma unroll
    for (int v = 0; v < 40; ++v) {
        float send = lo ? acc[v + 40] : acc[v];
        float got = __shfl_xor(send, 32);
        acc[v] += lo ? got : 0.f;
        acc[v + 40] += lo ? 0.f : got;
    }
#pragma unroll
    for (int v = 0; v < 40; ++v) {
        float x = lo ? acc[v] : acc[v + 40];
#pragma unroll
        for (int o = 16; o >= 1; o >>= 1) x += __shfl_xor(x, o);
        if ((lane & 31) == 0) lpart[wv][lo ? v : v + 40] = x;
    }
    __syncthreads();
    if (threadIdx.x < 80) {
        float v = lpart[0][threadIdx.x] + lpart[1][threadIdx.x] +
                  lpart[2][threadIdx.x] + lpart[3][threadIdx.x];
        ws[SPART_OFF + (size_t)(b * NSB + blockIdx.x) * 80 + threadIdx.x] = v;
    }
}

// 80 blocks x 256: one wave per output (320 outputs)
__global__ void k_centers2(float* __restrict__ ws) {
    int wv = threadIdx.x >> 6;
    int lane = threadIdx.x & 63;
    int gw = blockIdx.x * 4 + wv;        // 0..319
    int b = gw / 80, idx = gw - b * 80;
    const float* sp = ws + SPART_OFF + (size_t)b * NSB * 80 + idx;
    float x = sp[(size_t)lane * 80] + sp[(size_t)(lane + 64) * 80] +
              sp[(size_t)(lane + 128) * 80];
#pragma unroll
    for (int o = 32; o >= 1; o >>= 1) x += __shfl_xor(x, o);
    if (lane == 0) ws[ACC_OFF + b * 80 + idx] = x;
}

// Per-group compute body as a macro-free duplicated block is below in k_main.
__global__ __launch_bounds__(256, 3) void k_main(const float* __restrict__ yp,
                                                 const int* __restrict__ yt,
                                                 float* __restrict__ ws,
                                                 unsigned* __restrict__ hist) {
    int b = blockIdx.y;
    int lane = threadIdx.x & 63;
    int wv = threadIdx.x >> 6;
    __shared__ float ck_s[32];
    __shared__ float4 msw_s[17];
    __shared__ float part[4][2];
    __shared__ float bb[4];
    if (threadIdx.x < 16) {
        int k = threadIdx.x;
        const float* a = ws + ACC_OFF + (size_t)b * 80 + k * 5;
        float cnt = a[0];
        float safe = fmaxf(cnt, 1.0f);
        float inv = 1.0f / safe;
        ck_s[k * 2 + 0] = a[1] * inv;
        ck_s[k * 2 + 1] = a[2] * inv;
        float4 mw;
        mw.x = a[3] * inv;
        mw.y = a[4] * inv;
        mw.z = (cnt > 0.f) ? 0.5f / cnt : 0.f;
        mw.w = 0.f;
        msw_s[k] = mw;
    }
    if (threadIdx.x == 16) msw_s[16] = (float4){0.f, 0.f, 0.f, 0.f};
    __syncthreads();
    if (threadIdx.x == 0) {
        float ymin = 1e30f, ymax = -1e30f, xmin = 1e30f, xmax = -1e30f;
        for (int k = 0; k < Kdim; ++k) {
            float cnt = ws[ACC_OFF + (size_t)b * 80 + k * 5];
            if (cnt > 0.f) {
                float cy = ck_s[k * 2], cx = ck_s[k * 2 + 1];
                ymin = fminf(ymin, cy); ymax = fmaxf(ymax, cy);
                xmin = fminf(xmin, cx); xmax = fmaxf(xmax, cx);
            }
        }
        bb[0] = ymin; bb[1] = ymax; bb[2] = xmin; bb[3] = xmax;
    }
    __syncthreads();

    float cky[Kdim], ckx[Kdim];
#pragma unroll
    for (int k = 0; k < Kdim; ++k) {
        cky[k] = ck_s[k * 2];
        ckx[k] = ck_s[k * 2 + 1];
    }
    float bymin = bb[0], bymax = bb[1], bxmin = bb[2], bxmax = bb[3];

    unsigned* hb = hist + (size_t)(b * Kdim) * 2 * NBINS;
    unsigned* posnh = hist + (size_t)NHIST;
    const float4* bp4 = (const float4*)(yp + (size_t)b * 5 * HWPIX);
    const int4* bt4 = (const int4*)(yt + (size_t)b * HWPIX);

    int g0 = blockIdx.x * 256 + threadIdx.x;
    int g1 = g0 + GPI;
    int g2 = g0 + 2 * GPI;

    // ALL 18 loads issued up front (max outstanding-load concurrency/wave).
    float4 Aoy = bp4[g0], Aox = bp4[g0 + Q4], Asy = bp4[g0 + 2 * Q4];
    float4 Asx = bp4[g0 + 3 * Q4], Ase = bp4[g0 + 4 * Q4];
    int4 At = bt4[g0];
    float4 Boy = bp4[g1], Box = bp4[g1 + Q4], Bsy = bp4[g1 + 2 * Q4];
    float4 Bsx = bp4[g1 + 3 * Q4], Bse = bp4[g1 + 4 * Q4];
    int4 Bt = bt4[g1];
    float4 Coy = bp4[g2], Cox = bp4[g2 + Q4], Csy = bp4[g2 + 2 * Q4];
    float4 Csx = bp4[g2 + 3 * Q4], Cse = bp4[g2 + 4 * Q4];
    int4 Ct = bt4[g2];
    __builtin_amdgcn_sched_barrier(0);   // pin: all loads issued before compute

    float varsum = 0.f, ssum = 0.f;

    // ---------------- group A ----------------
    {
        int hwb = g0 * 4;
        float oy[4] = {Aoy.x, Aoy.y, Aoy.z, Aoy.w};
        float ox[4] = {Aox.x, Aox.y, Aox.z, Aox.w};
        float sya[4] = {Asy.x, Asy.y, Asy.z, Asy.w};
        float sxa[4] = {Asx.x, Asx.y, Asx.z, Asx.w};
        float sea[4] = {Ase.x, Ase.y, Ase.z, Ase.w};
        int tt[4] = {At.x, At.y, At.z, At.w};
#pragma unroll
        for (int j = 0; j < 4; ++j) {
            int hw = hwb + j;
            int h = hw / Wdim;
            int w = hw - h * Wdim;
            int own = tt[j] - 1;
            float sy = sya[j], sx = sxa[j];
            float ey = (float)h + oy[j], ex = (float)w + ox[j];
            float sby = fmaxf(sy, EPSf), sbx = fmaxf(sx, EPSf);
            float st = (own >= 0) ? EPSf : 0.f;
            float ry = RMARG * sby, rx = RMARG * sbx;
            bool maybe = (ey >= bymin - ry) && (ey <= bymax + ry) &&
                         (ex >= bxmin - rx) && (ex <= bxmax + rx);
            if (maybe) {
                float iy = 0.5f / (sby * sby), ix = 0.5f / (sbx * sbx);
                unsigned sm = 0;
#pragma unroll
                for (int k = 0; k < Kdim; ++k) {
                    float dy = ey - cky[k];
                    float dx = ex - ckx[k];
                    float q = fmaf(dy * dy, iy, dx * dx * ix);
                    if (q < QCLIP) sm |= (1u << k);
                }
                while (sm) {
                    int k = __ffs(sm) - 1;
                    sm &= sm - 1;
                    float dy = ey - ck_s[k * 2];
                    float dx = ex - ck_s[k * 2 + 1];
                    float q = fmaf(dy * dy, iy, dx * dx * ix);
                    float phi = expf(-q);
                    phi = fminf(fmaxf(phi, EPSf), 1.0f - EPSf);
                    float lg = logf(phi) - log1pf(-phi);
                    bool isPos = (k == own);
                    float e;
                    if (isPos) {
                        st = phi;
                        atomicAdd(&posnh[b * Kdim + k], 1u);
                        e = 1.0f - lg;
                    } else {
                        e = 1.0f + lg;
                    }
                    if (e > 0.f) {
                        int bin = (int)(e * INV_BIN_W);
                        if (bin > NBINS - 1) bin = NBINS - 1;
                        atomicAdd(&hb[(k * 2 + (isPos ? 1 : 0)) * NBINS + bin], 1u);
                    }
                }
            }
            int ow = (own >= 0) ? own : 16;
            float4 mw = msw_s[ow];
            float devv = fabsf(sy - mw.x) + fabsf(sx - mw.y);
            varsum = fmaf(devv, mw.z, varsum);
            float dd = sea[j] - st;
            ssum = fmaf(dd, dd, ssum);
        }
    }
    // ---------------- group B ----------------
    {
        int hwb = g1 * 4;
        float oy[4] = {Boy.x, Boy.y, Boy.z, Boy.w};
        float ox[4] = {Box.x, Box.y, Box.z, Box.w};
        float sya[4] = {Bsy.x, Bsy.y, Bsy.z, Bsy.w};
        float sxa[4] = {Bsx.x, Bsx.y, Bsx.z, Bsx.w};
        float sea[4] = {Bse.x, Bse.y, Bse.z, Bse.w};
        int tt[4] = {Bt.x, Bt.y, Bt.z, Bt.w};
#pragma unroll
        for (int j = 0; j < 4; ++j) {
            int hw = hwb + j;
            int h = hw / Wdim;
            int w = hw - h * Wdim;
            int own = tt[j] - 1;
            float sy = sya[j], sx = sxa[j];
            float ey = (float)h + oy[j], ex = (float)w + ox[j];
            float sby = fmaxf(sy, EPSf), sbx = fmaxf(sx, EPSf);
            float st = (own >= 0) ? EPSf : 0.f;
            float ry = RMARG * sby, rx = RMARG * sbx;
            bool maybe = (ey >= bymin - ry) && (ey <= bymax + ry) &&
                         (ex >= bxmin - rx) && (ex <= bxmax + rx);
            if (maybe) {
                float iy = 0.5f / (sby * sby), ix = 0.5f / (sbx * sbx);
                unsigned sm = 0;
#pragma unroll
                for (int k = 0; k < Kdim; ++k) {
                    float dy = ey - cky[k];
                    float dx = ex - ckx[k];
                    float q = fmaf(dy * dy, iy, dx * dx * ix);
                    if (q < QCLIP) sm |= (1u << k);
                }
                while (sm) {
                    int k = __ffs(sm) - 1;
                    sm &= sm - 1;
                    float dy = ey - ck_s[k * 2];
                    float dx = ex - ck_s[k * 2 + 1];
                    float q = fmaf(dy * dy, iy, dx * dx * ix);
                    float phi = expf(-q);
                    phi = fminf(fmaxf(phi, EPSf), 1.0f - EPSf);
                    float lg = logf(phi) - log1pf(-phi);
                    bool isPos = (k == own);
                    float e;
                    if (isPos) {
                        st = phi;
                        atomicAdd(&posnh[b * Kdim + k], 1u);
                        e = 1.0f - lg;
                    } else {
                        e = 1.0f + lg;
                    }
                    if (e > 0.f) {
                        int bin = (int)(e * INV_BIN_W);
                        if (bin > NBINS - 1) bin = NBINS - 1;
                        atomicAdd(&hb[(k * 2 + (isPos ? 1 : 0)) * NBINS + bin], 1u);
                    }
                }
            }
            int ow = (own >= 0) ? own : 16;
            float4 mw = msw_s[ow];
            float devv = fabsf(sy - mw.x) + fabsf(sx - mw.y);
            varsum = fmaf(devv, mw.z, varsum);
            float dd = sea[j] - st;
            ssum = fmaf(dd, dd, ssum);
        }
    }
    // ---------------- group C ----------------
    {
        int hwb = g2 * 4;
        float oy[4] = {Coy.x, Coy.y, Coy.z, Coy.w};
        float ox[4] = {Cox.x, Cox.y, Cox.z, Cox.w};
        float sya[4] = {Csy.x, Csy.y, Csy.z, Csy.w};
        float sxa[4] = {Csx.x, Csx.y, Csx.z, Csx.w};
        float sea[4] = {Cse.x, Cse.y, Cse.z, Cse.w};
        int tt[4] = {Ct.x, Ct.y, Ct.z, Ct.w};
#pragma unroll
        for (int j = 0; j < 4; ++j) {
            int hw = hwb + j;
            int h = hw / Wdim;
            int w = hw - h * Wdim;
            int own = tt[j] - 1;
            float sy = sya[j], sx = sxa[j];
            float ey = (float)h + oy[j], ex = (float)w + ox[j];
            float sby = fmaxf(sy, EPSf), sbx = fmaxf(sx, EPSf);
            float st = (own >= 0) ? EPSf : 0.f;
            float ry = RMARG * sby, rx = RMARG * sbx;
            bool maybe = (ey >= bymin - ry) && (ey <= bymax + ry) &&
                         (ex >= bxmin - rx) && (ex <= bxmax + rx);
            if (maybe) {
                float iy = 0.5f / (sby * sby), ix = 0.5f / (sbx * sbx);
                unsigned sm = 0;
#pragma unroll
                for (int k = 0; k < Kdim; ++k) {
                    float dy = ey - cky[k];
                    float dx = ex - ckx[k];
                    float q = fmaf(dy * dy, iy, dx * dx * ix);
                    if (q < QCLIP) sm |= (1u << k);
                }
                while (sm) {
                    int k = __ffs(sm) - 1;
                    sm &= sm - 1;
                    float dy = ey - ck_s[k * 2];
                    float dx = ex - ck_s[k * 2 + 1];
                    float q = fmaf(dy * dy, iy, dx * dx * ix);
                    float phi = expf(-q);
                    phi = fminf(fmaxf(phi, EPSf), 1.0f - EPSf);
                    float lg = logf(phi) - log1pf(-phi);
                    bool isPos = (k == own);
                    float e;
                    if (isPos) {
                        st = phi;
                        atomicAdd(&posnh[b * Kdim + k], 1u);
                        e = 1.0f - lg;
                    } else {
                        e = 1.0f + lg;
                    }
                    if (e > 0.f) {
                        int bin = (int)(e * INV_BIN_W);
                        if (bin > NBINS - 1) bin = NBINS - 1;
                        atomicAdd(&hb[(k * 2 + (isPos ? 1 : 0)) * NBINS + bin], 1u);
                    }
                }
            }
            int ow = (own >= 0) ? own : 16;
            float4 mw = msw_s[ow];
            float devv = fabsf(sy - mw.x) + fabsf(sx - mw.y);
            varsum = fmaf(devv, mw.z, varsum);
            float dd = sea[j] - st;
            ssum = fmaf(dd, dd, ssum);
        }
    }

#pragma unroll
    for (int o = 32; o >= 1; o >>= 1) {
        varsum += __shfl_xor(varsum, o);
        ssum += __shfl_xor(ssum, o);
    }
    if (lane == 0) {
        part[wv][0] = varsum;
        part[wv][1] = ssum;
    }
    __syncthreads();
    if (threadIdx.x < 2) {
        float v = part[0][threadIdx.x] + part[1][threadIdx.x] +
                  part[2][threadIdx.x] + part[3][threadIdx.x];
        ws[MPART_OFF + (size_t)(b * NSB + blockIdx.x) * 2 + threadIdx.x] = v;
    }
}

__global__ void k_lovasz(float* __restrict__ ws, const unsigned* __restrict__ hist) {
    int i = blockIdx.x;  // 0..63
    int lane = threadIdx.x;
    float P = ws[ACC_OFF + i * 5];
    if (P < 0.5f) {
        if (lane == 0) ws[LOVARR_OFF + i] = 0.f;
        return;
    }
    const unsigned* hn = hist + (size_t)i * 2 * NBINS;
    const unsigned* hp = hn + NBINS;
    const unsigned* posnh = hist + (size_t)NHIST;
    const float C_LO = logf(EPSf) - log1pf(-EPSf);
    const int HOTBIN = (int)((1.0f - C_LO) * INV_BIN_W);
    int deficit = (int)(P + 0.5f) - (int)posnh[i];
    int carry_p = 0, carry_n = 0;
    float Jtop = 0.f;
    float trap = 0.f;
    for (int c = NBINS / 64 - 1; c >= 0; --c) {
        int m = c * 64 + lane;
        int vp = (int)hp[m];
        int vn = (int)hn[m];
        if (m == HOTBIN) vp += deficit;
        for (int o = 1; o < 64; o <<= 1) {
            int tp = __shfl_down(vp, o);
            int tn = __shfl_down(vn, o);
            if (lane + o < 64) { vp += tp; vn += tn; }
        }
        float p_edge = (float)(carry_p + vp);
        float n_edge = (float)(carry_n + vn);
        float J = 1.0f - (P - p_edge) / (P + n_edge);
        float Jn = __shfl_down(J, 1);
        if (lane == 63) Jn = Jtop;
        trap += 0.5f * (J + Jn);
        carry_p += __shfl(vp, 0);
        carry_n += __shfl(vn, 0);
        Jtop = __shfl(J, 0);
    }
    for (int o = 1; o < 64; o <<= 1) {
        float t2 = __shfl_down(trap, o);
        if (lane + o < 64) trap += t2;
    }
    if (lane == 0) ws[LOVARR_OFF + i] = trap * BIN_W;
}

__global__ void k_final(const float* __restrict__ ws, float* __restrict__ out) {
    __shared__ float r0[256], r1[256], r2[256], r3[256];
    int t = threadIdx.x;
    float v = 0.f, s = 0.f, l = 0.f, pr = 0.f;
    for (int j = t; j < NBLK; j += 256) {
        v += ws[MPART_OFF + 2 * j];
        s += ws[MPART_OFF + 2 * j + 1];
    }
    if (t < 64) {
        l = ws[LOVARR_OFF + t];
        pr = (ws[ACC_OFF + t * 5] > 0.f) ? 1.f : 0.f;
    }
    r0[t] = v; r1[t] = s; r2[t] = l; r3[t] = pr;
    __syncthreads();
    for (int o = 128; o > 0; o >>= 1) {
        if (t < o) {
            r0[t] += r0[t + o]; r1[t] += r1[t + o];
            r2[t] += r2[t + o]; r3[t] += r3[t + o];
        }
        __syncthreads();
    }
    if (t == 0) {
        float npres = fmaxf(r3[0], 1.0f);
        out[0] = r2[0] / npres + 10.0f * (r0[0] / npres) +
                 r1[0] / (float)((size_t)Bdim * HWPIX);
    }
}

extern "C" void kernel_launch(void* const* d_in, const int* in_sizes, int n_in,
                              void* d_out, int out_size, void* d_ws, size_t ws_size,
                              hipStream_t stream) {
    const float* yp = (const float*)d_in[0];
    const int* yt = (const int*)d_in[1];
    float* ws = (float*)d_ws;
    unsigned* hist = (unsigned*)((char*)d_ws + HIST_OFF_F * 4);

    dim3 g(NSB, Bdim);
    k_stats<<<g, 256, 0, stream>>>(yp, yt, ws, hist);
    k_centers2<<<80, 256, 0, stream>>>(ws);
    k_main<<<g, 256, 0, stream>>>(yp, yt, ws, hist);
    k_lovasz<<<64, 64, 0, stream>>>(ws, hist);
    k_final<<<1, 256, 0, stream>>>(ws, (float*)d_out);
}